// Round 1
// baseline (384.581 us; speedup 1.0000x reference)
//
#include <hip/hip_runtime.h>
#include <stdint.h>

typedef _Float16 f16;
typedef _Float16 f16x8 __attribute__((ext_vector_type(8)));
typedef _Float16 f16x4 __attribute__((ext_vector_type(4)));
typedef float f32x4 __attribute__((ext_vector_type(4)));

#define S_TOK 8192
#define DDIM  512
#define L2E   1.44269504088896340736f
#define QSCALE 0.04419417382415922f   // 1/sqrt(512)

__device__ __forceinline__ void gload_lds16(const void* g, void* l) {
  __builtin_amdgcn_global_load_lds((const __attribute__((address_space(1))) void*)g,
                                   (__attribute__((address_space(3))) void*)l, 16, 0, 0);
}

// ---------------- convert f32 -> f16 (X and the three W matrices) -------------
__global__ __launch_bounds__(256) void k_convert(
    const float* __restrict__ X, const float* __restrict__ Wq,
    const float* __restrict__ Wk, const float* __restrict__ Wv,
    f16* __restrict__ Xh, f16* __restrict__ Wh) {
  const int SD = S_TOK * DDIM;        // 4194304
  const int DD = DDIM * DDIM;         // 262144
  int i4 = (blockIdx.x * 256 + threadIdx.x) * 4;
  if (i4 < SD) {
    f32x4 v = *(const f32x4*)(X + i4);
    f16x4 h = {(f16)v[0], (f16)v[1], (f16)v[2], (f16)v[3]};
    *(f16x4*)(Xh + i4) = h;
  } else {
    int j = i4 - SD;                  // < 3*DD
    int mat = j >> 18;                // DD = 2^18
    const float* src = (mat == 0) ? Wq : (mat == 1 ? Wk : Wv);
    f32x4 v = *(const f32x4*)(src + (j & (DD - 1)));
    f16x4 h = {(f16)v[0], (f16)v[1], (f16)v[2], (f16)v[3]};
    *(f16x4*)(Wh + j) = h;
  }
}

// ---------------- QKV projection: Y[8192 x 1536] = Xh @ Wh^T ------------------
// 128x128 tile, 4 waves (each 64x64), BK=64, fp16 MFMA, LDS xor-swizzled.
__global__ __launch_bounds__(256) void k_proj(
    const f16* __restrict__ Xh, const f16* __restrict__ Wh,
    f16* __restrict__ Qh, f16* __restrict__ Kh, f16* __restrict__ Vh) {
  __shared__ __align__(16) char Al[128 * 128];   // [128 rows][128B = 64 f16]
  __shared__ __align__(16) char Bl[128 * 128];
  const int tid = threadIdx.x;
  const int w = tid >> 6, lane = tid & 63;
  const int m0 = blockIdx.x * 128;
  const int n0 = blockIdx.y * 128;
  const int wr = (w >> 1) * 64;
  const int wc = (w & 1) * 64;

  f32x4 acc[4][4];
#pragma unroll
  for (int i = 0; i < 4; ++i)
#pragma unroll
    for (int j = 0; j < 4; ++j) acc[i][j] = (f32x4){0.f, 0.f, 0.f, 0.f};

  const char* Xb = (const char*)Xh;
  const char* Wb = (const char*)Wh;

  for (int kb = 0; kb < DDIM; kb += 64) {
    __syncthreads();
    // stage A,B tiles: 16 chunks of 1KB each (8 rows/chunk), 4 chunks per wave.
    // physical layout: phys_byte = row*128 + pcol, stored value = logical col pcol ^ ((row&7)<<4)
#pragma unroll
    for (int i = 0; i < 4; ++i) {
      int ch = w * 4 + i;
      int srow = lane >> 3;                               // row&7 within chunk
      int scol = ((lane & 7) * 16) ^ (srow << 4);         // pre-swizzled source col
      gload_lds16(Xb + (size_t)(m0 + ch * 8 + srow) * 1024 + kb * 2 + scol, Al + ch * 1024);
      gload_lds16(Wb + (size_t)(n0 + ch * 8 + srow) * 1024 + kb * 2 + scol, Bl + ch * 1024);
    }
    __syncthreads();
#pragma unroll
    for (int ks = 0; ks < 2; ++ks) {
      f16x8 a[4], b[4];
#pragma unroll
      for (int mf = 0; mf < 4; ++mf) {
        int row = wr + mf * 16 + (lane & 15);
        int col = (ks * 64 + ((lane >> 4) * 16)) ^ ((row & 7) << 4);
        a[mf] = *(const f16x8*)(Al + row * 128 + col);
      }
#pragma unroll
      for (int nf = 0; nf < 4; ++nf) {
        int row = wc + nf * 16 + (lane & 15);
        int col = (ks * 64 + ((lane >> 4) * 16)) ^ ((row & 7) << 4);
        b[nf] = *(const f16x8*)(Bl + row * 128 + col);
      }
#pragma unroll
      for (int mf = 0; mf < 4; ++mf)
#pragma unroll
        for (int nf = 0; nf < 4; ++nf)
          acc[mf][nf] = __builtin_amdgcn_mfma_f32_16x16x32_f16(a[mf], b[nf], acc[mf][nf], 0, 0, 0);
    }
  }
  // epilogue: whole block targets one matrix (n-tile of 128 within a 512 boundary)
  int mat = n0 >> 9;
  f16* dst = (mat == 0) ? Qh : (mat == 1 ? Kh : Vh);
  float scale = (mat == 0) ? QSCALE : 1.0f;
  int nbase = n0 & 511;
#pragma unroll
  for (int mf = 0; mf < 4; ++mf)
#pragma unroll
    for (int nf = 0; nf < 4; ++nf)
#pragma unroll
      for (int r = 0; r < 4; ++r) {
        int row = m0 + wr + mf * 16 + (lane >> 4) * 4 + r;
        int col = nbase + wc + nf * 16 + (lane & 15);
        dst[(size_t)row * DDIM + col] = (f16)(acc[mf][nf][r] * scale);
      }
}

// ---------------- V transpose: Vh[8192x512] -> Vt[512x8192] -------------------
__global__ __launch_bounds__(256) void k_transpose(
    const f16* __restrict__ Vh, f16* __restrict__ Vt) {
  __shared__ f16 T[64][66];   // +2 f16 pad: row stride 132B = 33 banks (coprime)
  int t = threadIdx.x;
  int s0 = blockIdx.x * 64;
  int d0 = blockIdx.y * 64;
#pragma unroll
  for (int p = 0; p < 2; ++p) {
    int row = p * 32 + (t >> 3);
    int c8 = (t & 7) * 8;
    f16x8 v = *(const f16x8*)(Vh + (size_t)(s0 + row) * DDIM + d0 + c8);
#pragma unroll
    for (int j = 0; j < 8; ++j) T[row][c8 + j] = v[j];
  }
  __syncthreads();
#pragma unroll
  for (int p = 0; p < 2; ++p) {
    int dr = p * 32 + (t >> 3);
    int c8 = (t & 7) * 8;
    f16x8 v;
#pragma unroll
    for (int j = 0; j < 8; ++j) v[j] = T[c8 + j][dr];
    *(f16x8*)(Vt + (size_t)(d0 + dr) * S_TOK + s0 + c8) = v;
  }
}

// ---------------- causal flash attention -------------------------------------
// 512 tasks = 256 Q-tiles (BM=32) x 2 D-halves (256 cols). Block b does tasks
// {b, 511-b} -> uniform ~129 KV-iterations per block. 8 waves:
//   QK^T : wave(wm=w>>2, wq=w&3) computes S[16x16] (rows wm*16, kv cols wq*16)
//   PV   : wave(wm, wq) computes O[16 rows x 64 cols] (d quarter wq)
__global__ __launch_bounds__(512) void k_flash(
    const f16* __restrict__ Qh, const f16* __restrict__ Kh,
    const f16* __restrict__ Vt, float* __restrict__ out) {
  __shared__ __align__(16) char Kl[64 * 1024];   // K tile [64][512 f16], swizzled
  __shared__ __align__(16) char Vl[256 * 128];   // V^T tile [256][64 f16], swizzled
  __shared__ float Sl[32 * 64];                  // raw scores
  __shared__ __align__(16) char Pl[32 * 128];    // P tile fp16, swizzled
  __shared__ float m_s[32], l_s[32], sc_s[32];

  const int tid = threadIdx.x;
  const int w = tid >> 6, lane = tid & 63;
  const int wm = w >> 2;    // 0..1 row half
  const int wq = w & 3;     // 0..3 kv quarter (QK) / d quarter (PV)

  for (int task_i = 0; task_i < 2; ++task_i) {
    int task = (task_i == 0) ? (int)blockIdx.x : (511 - (int)blockIdx.x);
    int t  = task >> 1;
    int c  = task & 1;
    int q0 = t * 32;
    int d0 = c * 256;

    if (tid < 32) { m_s[tid] = -3.0e38f; l_s[tid] = 0.0f; }

    // Q fragments in registers: rows q0 + wm*16 + (lane&15), all 16 k-steps
    f16x8 qf[16];
    {
      const f16* qp = Qh + (size_t)(q0 + wm * 16 + (lane & 15)) * DDIM + ((lane >> 4) * 8);
#pragma unroll
      for (int ks = 0; ks < 16; ++ks) qf[ks] = *(const f16x8*)(qp + ks * 32);
    }
    f32x4 acc[4];
#pragma unroll
    for (int i = 0; i < 4; ++i) acc[i] = (f32x4){0.f, 0.f, 0.f, 0.f};
    __syncthreads();

    int kend = q0 + 32;
    for (int kb = 0; kb < kend; kb += 64) {
      // ---- stage K [64 x 512] (8 chunks/wave) and V^T [256 x 64] (4 chunks/wave)
      {
        const char* Kb = (const char*)Kh;
#pragma unroll
        for (int i = 0; i < 8; ++i) {
          int ch = w * 8 + i;                                   // == K row
          int scol = (lane * 16) ^ ((ch & 7) << 4);
          gload_lds16(Kb + (size_t)(kb + ch) * 1024 + scol, Kl + ch * 1024);
        }
        const char* Vb = (const char*)Vt;
#pragma unroll
        for (int i = 0; i < 4; ++i) {
          int ch = w * 4 + i;
          int row = ch * 8 + (lane >> 3);                       // d-row within 256
          int scol = ((lane & 7) * 16) ^ ((lane >> 3) << 4);
          gload_lds16(Vb + (size_t)(d0 + row) * (S_TOK * 2) + kb * 2 + scol, Vl + ch * 1024);
        }
      }
      __syncthreads();   // staging visible (vmcnt(0) drained by barrier)

      // ---- QK^T: S[16x16] per wave over K=512
      {
        f32x4 s = (f32x4){0.f, 0.f, 0.f, 0.f};
        int krow = wq * 16 + (lane & 15);
        const char* kbase = Kl + krow * 1024;
        int sw = (krow & 7) << 4;
#pragma unroll
        for (int ks = 0; ks < 16; ++ks) {
          f16x8 kf = *(const f16x8*)(kbase + ((ks * 64 + ((lane >> 4) * 16)) ^ sw));
          s = __builtin_amdgcn_mfma_f32_16x16x32_f16(qf[ks], kf, s, 0, 0, 0);
        }
        int col = wq * 16 + (lane & 15);
        int rbase = wm * 16 + (lane >> 4) * 4;
#pragma unroll
        for (int r = 0; r < 4; ++r) Sl[(rbase + r) * 64 + col] = s[r];
      }
      __syncthreads();

      // ---- online softmax: wave handles rows w*4 .. w*4+3 (16 lanes per row)
      {
        int row = w * 4 + (lane >> 4);
        int cb = (lane & 15) * 4;
        f32x4 sv = *(const f32x4*)(Sl + row * 64 + cb);
        int qrow = q0 + row;
        float sm[4];
#pragma unroll
        for (int j = 0; j < 4; ++j) {
          float x = sv[j];
          if (kb + cb + j > qrow) x = -3.0e38f;   // causal mask
          sm[j] = x;
        }
        float mx = fmaxf(fmaxf(sm[0], sm[1]), fmaxf(sm[2], sm[3]));
#pragma unroll
        for (int off = 1; off < 16; off <<= 1) mx = fmaxf(mx, __shfl_xor(mx, off, 64));
        float m_old = m_s[row];
        float m_new = fmaxf(m_old, mx);
        float al = exp2f((m_old - m_new) * L2E);
        float p[4], ps = 0.f;
#pragma unroll
        for (int j = 0; j < 4; ++j) { p[j] = exp2f((sm[j] - m_new) * L2E); ps += p[j]; }
#pragma unroll
        for (int off = 1; off < 16; off <<= 1) ps += __shfl_xor(ps, off, 64);
        if ((lane & 15) == 0) {
          m_s[row] = m_new;
          l_s[row] = al * l_s[row] + ps;
          sc_s[row] = al;
        }
        f16x4 ph = {(f16)p[0], (f16)p[1], (f16)p[2], (f16)p[3]};
        int pcol = (cb * 2) ^ ((row & 7) << 4);
        *(f16x4*)(Pl + row * 128 + pcol) = ph;
      }
      __syncthreads();

      // ---- PV: rescale acc then O[16 x 64] += P[16x64] @ V^T
      {
        float scv[4];
        int rb = wm * 16 + (lane >> 4) * 4;
#pragma unroll
        for (int r = 0; r < 4; ++r) scv[r] = sc_s[rb + r];
#pragma unroll
        for (int nf = 0; nf < 4; ++nf)
#pragma unroll
          for (int r = 0; r < 4; ++r) acc[nf][r] *= scv[r];

        int prow = wm * 16 + (lane & 15);
        const char* pbase = Pl + prow * 128;
        int psw = (prow & 7) << 4;
#pragma unroll
        for (int ks = 0; ks < 2; ++ks) {
          f16x8 pa = *(const f16x8*)(pbase + ((ks * 64 + ((lane >> 4) * 16)) ^ psw));
#pragma unroll
          for (int nf = 0; nf < 4; ++nf) {
            int vrow = wq * 64 + nf * 16 + (lane & 15);
            f16x8 vb = *(const f16x8*)(Vl + vrow * 128 +
                         ((ks * 64 + ((lane >> 4) * 16)) ^ ((vrow & 7) << 4)));
            acc[nf] = __builtin_amdgcn_mfma_f32_16x16x32_f16(pa, vb, acc[nf], 0, 0, 0);
          }
        }
      }
      __syncthreads();   // protects K/V/S/P reuse next iteration
    }

    // ---- epilogue: O = acc / l
    {
      int rb = wm * 16 + (lane >> 4) * 4;
      float inv[4];
#pragma unroll
      for (int r = 0; r < 4; ++r) inv[r] = 1.0f / l_s[rb + r];
#pragma unroll
      for (int nf = 0; nf < 4; ++nf) {
        int col = d0 + wq * 64 + nf * 16 + (lane & 15);
#pragma unroll
        for (int r = 0; r < 4; ++r)
          out[(size_t)(q0 + rb + r) * DDIM + col] = acc[nf][r] * inv[r];
      }
    }
    __syncthreads();   // before next task's stats reinit
  }
}

extern "C" void kernel_launch(void* const* d_in, const int* in_sizes, int n_in,
                              void* d_out, int out_size, void* d_ws, size_t ws_size,
                              hipStream_t stream) {
  const float* X  = (const float*)d_in[0];
  // d_in[1] = causal mask, structurally known -> ignored
  const float* Wq = (const float*)d_in[2];
  const float* Wk = (const float*)d_in[3];
  const float* Wv = (const float*)d_in[4];
  float* out = (float*)d_out;

  char* ws = (char*)d_ws;
  f16* Xh = (f16*)(ws);                        //  8 MB
  f16* Wh = (f16*)(ws + (8u  << 20));          //  1.5 MB (Wq;Wk;Wv rows)
  f16* Qh = (f16*)(ws + (10u << 20));          //  8 MB (pre-scaled by 1/sqrt(D))
  f16* Kh = (f16*)(ws + (18u << 20));          //  8 MB
  f16* Vh = (f16*)(ws + (26u << 20));          //  8 MB
  f16* Vt = (f16*)(ws + (34u << 20));          //  8 MB  (total 42 MB)

  k_convert<<<4864, 256, 0, stream>>>(X, Wq, Wk, Wv, Xh, Wh);
  dim3 gp(64, 12);
  k_proj<<<gp, 256, 0, stream>>>(Xh, Wh, Qh, Kh, Vh);
  dim3 gt(128, 8);
  k_transpose<<<gt, 256, 0, stream>>>(Vh, Vt);
  k_flash<<<256, 512, 0, stream>>>(Qh, Kh, Vt, out);
}

// Round 2
// 290.363 us; speedup vs baseline: 1.3245x; 1.3245x over previous
//
#include <hip/hip_runtime.h>
#include <stdint.h>

typedef _Float16 f16;
typedef _Float16 f16x8 __attribute__((ext_vector_type(8)));
typedef _Float16 f16x4 __attribute__((ext_vector_type(4)));
typedef float f32x4 __attribute__((ext_vector_type(4)));

#define S_TOK 8192
#define DDIM  512
#define L2E   1.44269504088896340736f
#define QSCALE 0.04419417382415922f   // 1/sqrt(512)
#define NSLOT 320
#define GTOT  8320                    // total KVB=32 iterations over all 64 tiles

__device__ __forceinline__ void gload_lds16(const void* g, void* l) {
  __builtin_amdgcn_global_load_lds((const __attribute__((address_space(1))) void*)g,
                                   (__attribute__((address_space(3))) void*)l, 16, 0, 0);
}

// ---------------- init slot-tile table -----------------------------------
__global__ void k_init(int* tp) {
  int i = blockIdx.x * 64 + threadIdx.x;
  if (i < NSLOT) tp[i] = -1;
}

// ---------------- convert f32 -> f16 (X and the three W matrices) --------
__global__ __launch_bounds__(256) void k_convert(
    const float* __restrict__ X, const float* __restrict__ Wq,
    const float* __restrict__ Wk, const float* __restrict__ Wv,
    f16* __restrict__ Xh, f16* __restrict__ Wh) {
  const int SD = S_TOK * DDIM;
  const int DD = DDIM * DDIM;
  int i4 = (blockIdx.x * 256 + threadIdx.x) * 4;
  if (i4 < SD) {
    f32x4 v = *(const f32x4*)(X + i4);
    f16x4 h = {(f16)v[0], (f16)v[1], (f16)v[2], (f16)v[3]};
    *(f16x4*)(Xh + i4) = h;
  } else {
    int j = i4 - SD;
    int mat = j >> 18;
    const float* src = (mat == 0) ? Wq : (mat == 1 ? Wk : Wv);
    f32x4 v = *(const f32x4*)(src + (j & (DD - 1)));
    f16x4 h = {(f16)v[0], (f16)v[1], (f16)v[2], (f16)v[3]};
    *(f16x4*)(Wh + j) = h;
  }
}

// ---------------- QKV projection: Y[8192 x 1536] = Xh @ Wh^T -------------
// 128x128 tile, 4 waves (each 64x64), BK=64, fp16 MFMA, LDS xor-swizzled.
// Q,K written row-major (Q pre-scaled). V written in packed MFMA-B-frag
// order: VB[K=s/32][f=d/16][lane*16 + j*2] with value(lane,j) =
//   V[K*32 + (lane>>4)*8 + j][f*16 + (lane&15)]
__global__ __launch_bounds__(256) void k_proj(
    const f16* __restrict__ Xh, const f16* __restrict__ Wh,
    f16* __restrict__ Qh, f16* __restrict__ Kh, f16* __restrict__ VB) {
  __shared__ __align__(16) char Al[128 * 128];
  __shared__ __align__(16) char Bl[128 * 128];
  const int tid = threadIdx.x;
  const int w = tid >> 6, lane = tid & 63;
  const int m0 = blockIdx.x * 128;
  const int n0 = blockIdx.y * 128;
  const int wr = (w >> 1) * 64;
  const int wc = (w & 1) * 64;

  f32x4 acc[4][4];
#pragma unroll
  for (int i = 0; i < 4; ++i)
#pragma unroll
    for (int j = 0; j < 4; ++j) acc[i][j] = (f32x4){0.f, 0.f, 0.f, 0.f};

  const char* Xb = (const char*)Xh;
  const char* Wb = (const char*)Wh;

  for (int kb = 0; kb < DDIM; kb += 64) {
    __syncthreads();
#pragma unroll
    for (int i = 0; i < 4; ++i) {
      int ch = w * 4 + i;
      int srow = lane >> 3;
      int scol = ((lane & 7) * 16) ^ (srow << 4);
      gload_lds16(Xb + (size_t)(m0 + ch * 8 + srow) * 1024 + kb * 2 + scol, Al + ch * 1024);
      gload_lds16(Wb + (size_t)(n0 + ch * 8 + srow) * 1024 + kb * 2 + scol, Bl + ch * 1024);
    }
    __syncthreads();
#pragma unroll
    for (int ks = 0; ks < 2; ++ks) {
      f16x8 a[4], b[4];
#pragma unroll
      for (int mf = 0; mf < 4; ++mf) {
        int row = wr + mf * 16 + (lane & 15);
        int col = (ks * 64 + ((lane >> 4) * 16)) ^ ((row & 7) << 4);
        a[mf] = *(const f16x8*)(Al + row * 128 + col);
      }
#pragma unroll
      for (int nf = 0; nf < 4; ++nf) {
        int row = wc + nf * 16 + (lane & 15);
        int col = (ks * 64 + ((lane >> 4) * 16)) ^ ((row & 7) << 4);
        b[nf] = *(const f16x8*)(Bl + row * 128 + col);
      }
#pragma unroll
      for (int mf = 0; mf < 4; ++mf)
#pragma unroll
        for (int nf = 0; nf < 4; ++nf)
          acc[mf][nf] = __builtin_amdgcn_mfma_f32_16x16x32_f16(a[mf], b[nf], acc[mf][nf], 0, 0, 0);
    }
  }
  int mat = n0 >> 9;
  int nbase = n0 & 511;
  if (mat == 2) {
#pragma unroll
    for (int mf = 0; mf < 4; ++mf) {
      int R0 = m0 + wr + mf * 16 + (lane >> 4) * 4;   // 4-aligned token row
      int K = R0 >> 5;
      int lhi = ((R0 >> 3) & 3) * 16;
      int j0 = R0 & 7;                                // 0 or 4
#pragma unroll
      for (int nf = 0; nf < 4; ++nf) {
        int col = nbase + wc + nf * 16 + (lane & 15);
        f16x4 h = {(f16)acc[mf][nf][0], (f16)acc[mf][nf][1],
                   (f16)acc[mf][nf][2], (f16)acc[mf][nf][3]};
        *(f16x4*)((char*)VB + (size_t)(K * 32 + (col >> 4)) * 1024 +
                  (lhi + (col & 15)) * 16 + j0 * 2) = h;
      }
    }
  } else {
    f16* dst = (mat == 0) ? Qh : Kh;
    float scale = (mat == 0) ? QSCALE : 1.0f;
#pragma unroll
    for (int mf = 0; mf < 4; ++mf)
#pragma unroll
      for (int nf = 0; nf < 4; ++nf)
#pragma unroll
        for (int r = 0; r < 4; ++r) {
          int row = m0 + wr + mf * 16 + (lane >> 4) * 4 + r;
          int col = nbase + wc + nf * 16 + (lane & 15);
          dst[(size_t)row * DDIM + col] = (f16)(acc[mf][nf][r] * scale);
        }
  }
}

// ---------------- causal flash attention, BM=128, KVB=32, split-KV -------
// 256 blocks; global iteration space [0,8320) split evenly (32-33 iters).
// Tile t (q0=t*128) covers g in [2t(t+1), 2(t+1)(t+2)). Each (block,tile)
// part writes f16 partial O/l + (m,l) to slot b + t (unique, < 320).
__global__ __launch_bounds__(512, 2) void k_flash(
    const f16* __restrict__ Qh, const f16* __restrict__ Kh,
    const f16* __restrict__ VBg, f16* __restrict__ Opart,
    float* __restrict__ Mpart, float* __restrict__ Lpart,
    int* __restrict__ TilePart) {
  __shared__ __align__(16) char Kl[2][32768];   // K tile [32][512 f16] swizzled
  __shared__ __align__(16) char Vl[2][32768];   // V frag-packed [32 frags][1KB]
  __shared__ __align__(16) char Pl[8][1024];    // per-wave P [16][32] f16 swz

  const int tid = threadIdx.x;
  const int w = tid >> 6, lane = tid & 63;
  const int l15 = lane & 15, l4 = lane >> 4;

  int bid = blockIdx.x;
  int b = (bid & 7) * 32 + (bid >> 3);          // XCD-contiguous logical id
  int g  = (GTOT * b) >> 8;
  int g1 = (GTOT * (b + 1)) >> 8;
  int t = 0;
  while (2 * (t + 1) * (t + 2) <= g) ++t;

  const char* Kb = (const char*)Kh;
  const char* Vb = (const char*)VBg;

  while (g < g1) {
    int Ct  = 2 * t * (t + 1);
    int Ct1 = 2 * (t + 1) * (t + 2);
    int gend = min(g1, Ct1);
    int n = gend - g;
    int kb0 = (g - Ct) * 32;
    int q0 = t * 128;
    int slot = b + t;

    // Q fragments: rows q0 + w*16 + l15, full D
    f16x8 qf[16];
    {
      const f16* qp = Qh + (size_t)(q0 + w * 16 + l15) * DDIM + l4 * 8;
#pragma unroll
      for (int ks = 0; ks < 16; ++ks) qf[ks] = *(const f16x8*)(qp + ks * 32);
    }
    f32x4 acc[32];
#pragma unroll
    for (int i = 0; i < 32; ++i) acc[i] = (f32x4){0.f, 0.f, 0.f, 0.f};
    float mreg[4], lreg[4];
#pragma unroll
    for (int r = 0; r < 4; ++r) { mreg[r] = -3.0e38f; lreg[r] = 0.f; }

    // prologue: stage buf0
    {
#pragma unroll
      for (int i = 0; i < 4; ++i) {
        int row = w * 4 + i;
        int scol = (lane * 16) ^ ((row & 7) << 4);
        gload_lds16(Kb + (size_t)(kb0 + row) * 1024 + scol, Kl[0] + row * 1024);
      }
      const char* vs = Vb + (size_t)(kb0 >> 5) * 32768;
#pragma unroll
      for (int i = 0; i < 4; ++i) {
        int ch = w * 4 + i;
        gload_lds16(vs + ch * 1024 + lane * 16, Vl[0] + ch * 1024);
      }
    }

    for (int it = 0; it < n; ++it) {
      int cur = it & 1;
      if (it + 1 < n) {
        int kb = kb0 + (it + 1) * 32;
#pragma unroll
        for (int i = 0; i < 4; ++i) {
          int row = w * 4 + i;
          int scol = (lane * 16) ^ ((row & 7) << 4);
          gload_lds16(Kb + (size_t)(kb + row) * 1024 + scol, Kl[cur ^ 1] + row * 1024);
        }
        const char* vs = Vb + (size_t)(kb >> 5) * 32768;
#pragma unroll
        for (int i = 0; i < 4; ++i) {
          int ch = w * 4 + i;
          gload_lds16(vs + ch * 1024 + lane * 16, Vl[cur ^ 1] + ch * 1024);
        }
        asm volatile("s_waitcnt vmcnt(8)" ::: "memory");  // prev stage drained
      } else {
        asm volatile("s_waitcnt vmcnt(0)" ::: "memory");
      }
      __builtin_amdgcn_s_barrier();

      int kb = kb0 + it * 32;
      const char* KlB = Kl[cur];
      const char* VlB = Vl[cur];

      // ---- QK^T: S[16 x 32] per wave over d=512
      f32x4 s0 = (f32x4){0.f, 0.f, 0.f, 0.f};
      f32x4 s1 = (f32x4){0.f, 0.f, 0.f, 0.f};
#pragma unroll
      for (int ks = 0; ks < 16; ++ks) {
        int off = ks * 64 + l4 * 16;
        {
          int krow = l15;
          f16x8 kf = *(const f16x8*)(KlB + krow * 1024 + (off ^ ((krow & 7) << 4)));
          s0 = __builtin_amdgcn_mfma_f32_16x16x32_f16(qf[ks], kf, s0, 0, 0, 0);
        }
        {
          int krow = 16 + l15;
          f16x8 kf = *(const f16x8*)(KlB + krow * 1024 + (off ^ ((krow & 7) << 4)));
          s1 = __builtin_amdgcn_mfma_f32_16x16x32_f16(qf[ks], kf, s1, 0, 0, 0);
        }
      }

      // ---- online softmax, fully in registers
      float p0[4], p1[4], mx[4];
      int qrb = q0 + w * 16 + l4 * 4;
      int kc = kb + l15;
#pragma unroll
      for (int r = 0; r < 4; ++r) {
        int qr = qrb + r;
        float x0 = (kc      <= qr) ? s0[r] : -3.0e38f;
        float x1 = (kc + 16 <= qr) ? s1[r] : -3.0e38f;
        p0[r] = x0; p1[r] = x1;
        float m = fmaxf(x0, x1);
        m = fmaxf(m, __shfl_xor(m, 1, 64));
        m = fmaxf(m, __shfl_xor(m, 2, 64));
        m = fmaxf(m, __shfl_xor(m, 4, 64));
        m = fmaxf(m, __shfl_xor(m, 8, 64));
        mx[r] = m;
      }
      bool need = (mx[0] > mreg[0] + 8.f) || (mx[1] > mreg[1] + 8.f) ||
                  (mx[2] > mreg[2] + 8.f) || (mx[3] > mreg[3] + 8.f);
      if (__any(need)) {                       // T13 defer-rescale, THR=8
#pragma unroll
        for (int r = 0; r < 4; ++r) {
          float mn = fmaxf(mreg[r], mx[r]);
          float al = exp2f((mreg[r] - mn) * L2E);
          lreg[r] *= al;
          mreg[r] = mn;
          mx[r] = al;
        }
#pragma unroll
        for (int nf = 0; nf < 32; ++nf)
#pragma unroll
          for (int r = 0; r < 4; ++r) acc[nf][r] *= mx[r];
      }
      // P = exp(s - m), row-sum into l
#pragma unroll
      for (int r = 0; r < 4; ++r) {
        int qr = qrb + r;
        float e0 = (kc      <= qr) ? exp2f((p0[r] - mreg[r]) * L2E) : 0.f;
        float e1 = (kc + 16 <= qr) ? exp2f((p1[r] - mreg[r]) * L2E) : 0.f;
        p0[r] = e0; p1[r] = e1;
        float ss = e0 + e1;
        ss += __shfl_xor(ss, 1, 64);
        ss += __shfl_xor(ss, 2, 64);
        ss += __shfl_xor(ss, 4, 64);
        ss += __shfl_xor(ss, 8, 64);
        lreg[r] += ss;
      }
      // P -> wave-private LDS (C-layout write, A-layout read), swizzled
      char* Pw = Pl[w];
#pragma unroll
      for (int r = 0; r < 4; ++r) {
        int row = l4 * 4 + r;
        int sw = (((row & 3) ^ (row >> 2)) & 3) << 4;
        *(f16*)(Pw + row * 64 + ((l15 * 2) ^ sw))          = (f16)p0[r];
        *(f16*)(Pw + row * 64 + (((16 + l15) * 2) ^ sw))   = (f16)p1[r];
      }
      // ---- PV: O[16 x 512] += P[16 x 32] @ V[32 x 512]
      {
        int prow = l15;
        int sw = (((prow & 3) ^ (prow >> 2)) & 3) << 4;
        f16x8 pa = *(const f16x8*)(Pw + prow * 64 + ((l4 * 16) ^ sw));
#pragma unroll
        for (int nf = 0; nf < 32; ++nf) {
          f16x8 vb = *(const f16x8*)(VlB + nf * 1024 + lane * 16);
          acc[nf] = __builtin_amdgcn_mfma_f32_16x16x32_f16(pa, vb, acc[nf], 0, 0, 0);
        }
      }
      __builtin_amdgcn_s_barrier();
    }

    // ---- part epilogue: normalized f16 partial + stats
    {
      float invl[4];
#pragma unroll
      for (int r = 0; r < 4; ++r) invl[r] = (lreg[r] > 0.f) ? 1.f / lreg[r] : 0.f;
      f16* op = Opart + (size_t)slot * (128 * 512);
      int rowb = w * 16 + l4 * 4;
#pragma unroll
      for (int nf = 0; nf < 32; ++nf) {
        int col = nf * 16 + l15;
#pragma unroll
        for (int r = 0; r < 4; ++r)
          op[(rowb + r) * 512 + col] = (f16)(acc[nf][r] * invl[r]);
      }
      if (l15 == 0) {
#pragma unroll
        for (int r = 0; r < 4; ++r) {
          Mpart[slot * 128 + rowb + r] = mreg[r];
          Lpart[slot * 128 + rowb + r] = lreg[r];
        }
      }
      if (tid == 0) TilePart[slot] = t;
    }
    g = gend;
    ++t;
  }
}

// ---------------- combine partials -> out --------------------------------
__global__ __launch_bounds__(256) void k_reduce(
    const f16* __restrict__ Opart, const float* __restrict__ Mpart,
    const float* __restrict__ Lpart, const int* __restrict__ TilePart,
    float* __restrict__ out) {
  __shared__ int tp[NSLOT];
  __shared__ int sl[16];
  __shared__ int scnt;
  int tid = threadIdx.x;
  int t = blockIdx.x >> 2, rg = blockIdx.x & 3;
  for (int s = tid; s < NSLOT; s += 256) tp[s] = TilePart[s];
  __syncthreads();
  if (tid == 0) {
    int c = 0;
    for (int s = 0; s < NSLOT; ++s)
      if (tp[s] == t && c < 16) sl[c++] = s;
    scnt = c;
  }
  __syncthreads();
  int cnt = scnt;
  int rowIn = rg * 32 + (tid >> 3);
  int row = t * 128 + rowIn;
  int col0 = (tid & 7) * 64;

  float M = -3.0e38f;
  for (int i = 0; i < cnt; ++i) M = fmaxf(M, Mpart[sl[i] * 128 + rowIn]);
  float a[64];
#pragma unroll
  for (int j = 0; j < 64; ++j) a[j] = 0.f;
  float denom = 0.f;
  for (int i = 0; i < cnt; ++i) {
    int s = sl[i];
    float m = Mpart[s * 128 + rowIn];
    float l = Lpart[s * 128 + rowIn];
    float wgt = exp2f((m - M) * L2E) * l;
    denom += wgt;
    const f16* op = Opart + (size_t)s * 65536 + rowIn * 512 + col0;
#pragma unroll
    for (int v = 0; v < 8; ++v) {
      f16x8 x = *(const f16x8*)(op + v * 8);
#pragma unroll
      for (int j = 0; j < 8; ++j) a[v * 8 + j] += wgt * (float)x[j];
    }
  }
  float inv = (denom > 0.f) ? 1.f / denom : 0.f;
  float* o = out + (size_t)row * 512 + col0;
#pragma unroll
  for (int j = 0; j < 64; ++j) o[j] = a[j] * inv;
}

extern "C" void kernel_launch(void* const* d_in, const int* in_sizes, int n_in,
                              void* d_out, int out_size, void* d_ws, size_t ws_size,
                              hipStream_t stream) {
  const float* X  = (const float*)d_in[0];
  const float* Wq = (const float*)d_in[2];
  const float* Wk = (const float*)d_in[3];
  const float* Wv = (const float*)d_in[4];
  float* out = (float*)d_out;

  char* ws = (char*)d_ws;
  f16*   Opart = (f16*)(ws);                               // 40 MiB
  float* Mpart = (float*)(ws + (40u << 20));               // 160 KiB
  float* Lpart = (float*)(ws + (41u << 20));               // 160 KiB
  int*   TileP = (int*)(ws + (42u << 20));                 // 1.25 KiB
  f16* Qh = (f16*)(ws + (43u << 20));                      // 8 MiB (pre-scaled)
  f16* Kh = (f16*)(ws + (51u << 20));                      // 8 MiB
  f16* VB = (f16*)(ws + (59u << 20));                      // 8 MiB packed frags
  f16* Xh = (f16*)(ws + (67u << 20));                      // 8 MiB
  f16* Wh = (f16*)(ws + (75u << 20));                      // 1.5 MiB

  k_init<<<5, 64, 0, stream>>>(TileP);
  k_convert<<<4864, 256, 0, stream>>>(X, Wq, Wk, Wv, Xh, Wh);
  dim3 gp(64, 12);
  k_proj<<<gp, 256, 0, stream>>>(Xh, Wh, Qh, Kh, VB);
  k_flash<<<256, 512, 0, stream>>>(Qh, Kh, VB, Opart, Mpart, Lpart, TileP);
  k_reduce<<<256, 256, 0, stream>>>(Opart, Mpart, Lpart, TileP, out);
}